// Round 5
// baseline (19.086 us; speedup 1.0000x reference)
//
#include <hip/hip_runtime.h>

// Problem constants (fixed by setup_inputs)
#define BB 16
#define SS 1024
#define NW 8
#define QB 32     // q rows per block -> 512 blocks = 2 blocks/CU, 32 waves/CU
#define PS 1032   // LDS plane stride in words; 1032 % 32 == 8 staggers head planes

typedef float v2f __attribute__((ext_vector_type(2)));

__global__ __launch_bounds__(1024, 8)
void mhaq_kernel(const float* __restrict__ x,      // (B,S,8) f32
                 const int*   __restrict__ mask,   // (B,S)
                 const float* __restrict__ theta,  // (8,)
                 const float* __restrict__ wout,   // (8,8)
                 float* __restrict__ out)          // (B,S,8) f32
{
    __shared__ float P[8 * PS];    // U planes [hd][PS] (mask-folded), then V planes
    __shared__ float Qf[QB][NW];   // unmasked q features, pre-scaled by log2e/sqrt(2)
    __shared__ float O[QB][NW];    // attention outputs pre-projection
    __shared__ float W[NW * NW];   // w_out

    const int tid = threadIdx.x;
    const int b   = blockIdx.x >> 5;   // 32 q-chunks per batch row
    const int qc  = blockIdx.x & 31;

    // ---- stage quantum head for row k = tid (closed form), mask folded into K planes.
    // g_i = cos(x_i + theta_i); h_0 = g1..g7, h_w = g0..gw (w>=1)
    int cm;
    {
        float th[NW];
#pragma unroll
        for (int e = 0; e < NW; ++e) th[e] = theta[e];
        const float* xr = x + ((size_t)b * SS + tid) * NW;
        const float4 r0 = *reinterpret_cast<const float4*>(xr);
        const float4 r1 = *reinterpret_cast<const float4*>(xr + 4);
        float g[NW];
        g[0] = __cosf(r0.x + th[0]); g[1] = __cosf(r0.y + th[1]);
        g[2] = __cosf(r0.z + th[2]); g[3] = __cosf(r0.w + th[3]);
        g[4] = __cosf(r1.x + th[4]); g[5] = __cosf(r1.y + th[5]);
        g[6] = __cosf(r1.z + th[6]); g[7] = __cosf(r1.w + th[7]);
        float h[NW];
        h[1] = g[0] * g[1]; h[2] = h[1] * g[2]; h[3] = h[2] * g[3];
        h[4] = h[3] * g[4]; h[5] = h[4] * g[5]; h[6] = h[5] * g[6];
        h[7] = h[6] * g[7];
        h[0] = (g[1] * g[2]) * (g[3] * g[4]) * ((g[5] * g[6]) * g[7]);
        const float mf = (mask[b * SS + tid] != 0) ? 1.0f : 0.0f;
#pragma unroll
        for (int p = 0; p < 4; ++p) {
            P[p * PS + tid]       = h[2 * p]     * mf;  // U plane
            P[(4 + p) * PS + tid] = h[2 * p + 1] * mf;  // V plane
        }
        const int r = tid - qc * QB;
        if ((unsigned)r < (unsigned)QB) {  // one of this block's q-rows
            const float CF = 0.70710678118654752f * 1.44269504088896340f;
#pragma unroll
            for (int w = 0; w < NW; ++w) Qf[r][w] = h[w] * CF;
        }
        if (tid < NW * NW) W[tid] = wout[tid];
        // masked-key count (each masked key contributes exp2(0)=1 to d); also the barrier
        cm = __syncthreads_count(mf == 0.0f);
    }

    // ---- per-thread role: 4 q-rows, one head, 1-of-32 k-slices
    const int qg = tid >> 7;         // 0..7  -> q rows qg*4..qg*4+3
    const int hd = (tid >> 5) & 3;   // 0..3
    const int ks = tid & 31;         // 0..31 (reduced via shfl, low 5 lane bits)

    float qu[4], qv[4];
#pragma unroll
    for (int i = 0; i < 4; ++i) {
        qu[i] = Qf[qg * 4 + i][2 * hd];
        qv[i] = Qf[qg * 4 + i][2 * hd + 1];
    }

    v2f vd[4], va0[4], va1[4];
#pragma unroll
    for (int i = 0; i < 4; ++i) {
        vd[i] = (v2f){0.f, 0.f}; va0[i] = (v2f){0.f, 0.f}; va1[i] = (v2f){0.f, 0.f};
    }

    // k's per thread: 4*ks + 128*t + {0..3}, t = 0..7  (32 k's, 128 exps)
    const int base0 = hd * PS + 4 * ks;
#pragma unroll
    for (int t = 0; t < 8; ++t) {
        const int a = base0 + 128 * t;
        const float4 Ur = *reinterpret_cast<const float4*>(&P[a]);
        const float4 Vr = *reinterpret_cast<const float4*>(&P[4 * PS + a]);
        const v2f ulo = (v2f){Ur.x, Ur.y}, uhi = (v2f){Ur.z, Ur.w};
        const v2f vlo = (v2f){Vr.x, Vr.y}, vhi = (v2f){Vr.z, Vr.w};
#pragma unroll
        for (int i = 0; i < 4; ++i) {
            const v2f qup = (v2f){qu[i], qu[i]};
            const v2f qvp = (v2f){qv[i], qv[i]};
            const v2f slo = __builtin_elementwise_fma(qup, ulo, qvp * vlo);
            const v2f shi = __builtin_elementwise_fma(qup, uhi, qvp * vhi);
            const v2f wlo = (v2f){__builtin_amdgcn_exp2f(slo.x), __builtin_amdgcn_exp2f(slo.y)};
            const v2f whi = (v2f){__builtin_amdgcn_exp2f(shi.x), __builtin_amdgcn_exp2f(shi.y)};
            vd[i]  += wlo + whi;
            va0[i] = __builtin_elementwise_fma(wlo, ulo, va0[i]);
            va0[i] = __builtin_elementwise_fma(whi, uhi, va0[i]);
            va1[i] = __builtin_elementwise_fma(wlo, vlo, va1[i]);
            va1[i] = __builtin_elementwise_fma(whi, vhi, va1[i]);
        }
    }

    // ---- collapse packed lanes, reduce across the 32 k-slices (low 5 lane bits)
    float dd[4], a0[4], a1[4];
#pragma unroll
    for (int i = 0; i < 4; ++i) {
        dd[i] = vd[i].x + vd[i].y;
        a0[i] = va0[i].x + va0[i].y;
        a1[i] = va1[i].x + va1[i].y;
    }
#pragma unroll
    for (int m = 1; m <= 16; m <<= 1) {
#pragma unroll
        for (int i = 0; i < 4; ++i) {
            dd[i] += __shfl_xor(dd[i], m);
            a0[i] += __shfl_xor(a0[i], m);
            a1[i] += __shfl_xor(a1[i], m);
        }
    }
    if (ks == 0) {
#pragma unroll
        for (int i = 0; i < 4; ++i) {
            const float inv = 1.0f / (dd[i] - (float)cm);
            O[qg * 4 + i][2 * hd]     = a0[i] * inv;
            O[qg * 4 + i][2 * hd + 1] = a1[i] * inv;
        }
    }
    __syncthreads();

    // ---- output projection: out = O @ W^T (f32)
    if (tid < QB * NW) {
        const int q = tid >> 3, e = tid & 7;
        float s = 0.f;
#pragma unroll
        for (int f = 0; f < NW; ++f) s = __builtin_fmaf(O[q][f], W[e * NW + f], s);
        out[((size_t)(b * SS + qc * QB + q)) * NW + e] = s;
    }
}

extern "C" void kernel_launch(void* const* d_in, const int* in_sizes, int n_in,
                              void* d_out, int out_size, void* d_ws, size_t ws_size,
                              hipStream_t stream) {
    const float* x     = (const float*)d_in[0];
    const int*   mask  = (const int*)d_in[1];
    const float* theta = (const float*)d_in[2];
    const float* wout  = (const float*)d_in[3];
    float* out = (float*)d_out;

    dim3 grid(BB * (SS / QB));  // 512 blocks -> 2 blocks/CU
    dim3 block(1024);           // 32 waves/CU, 8 per SIMD
    mhaq_kernel<<<grid, block, 0, stream>>>(x, mask, theta, wout, out);
}

// Round 6
// 15.356 us; speedup vs baseline: 1.2429x; 1.2429x over previous
//
#include <hip/hip_runtime.h>

// Problem constants (fixed by setup_inputs)
#define BB 16
#define SS 1024
#define NW 8
#define QB 64
#define NH 4
#define NM 55            // moments (j,i), j+i <= 9
#define NJOB (NH * NM)   // 220

// ws layout (floats):
//   feats    : [BB][SS][NW]        = 131072 floats (unmasked h features)
//   partials : [BB][16][NJOB]      = 56320 floats  (per-chunk partial moments)
#define WS_FEAT 0
#define WS_PART (BB * SS * NW)

// ---------------- K1: features + partial moment tables ----------------
__global__ __launch_bounds__(1024)
void mhaq_k1(const float* __restrict__ x, const int* __restrict__ mask,
             const float* __restrict__ theta, float* __restrict__ ws)
{
    __shared__ float P[NH][QB][4];   // per (head, local row): u, v, mf, 0

    const int tid = threadIdx.x;
    const int b   = blockIdx.x >> 4;
    const int qc  = blockIdx.x & 15;

    // ---- stage: rows qc*64..+63. g_i = cos(x_i + th_i); h0 = g1..g7, hw = g0..gw
    if (tid < QB) {
        const int row = qc * QB + tid;
        const float* xr = x + ((size_t)b * SS + row) * NW;
        const float4 r0 = *reinterpret_cast<const float4*>(xr);
        const float4 r1 = *reinterpret_cast<const float4*>(xr + 4);
        float g[NW];
        g[0] = __cosf(r0.x + theta[0]); g[1] = __cosf(r0.y + theta[1]);
        g[2] = __cosf(r0.z + theta[2]); g[3] = __cosf(r0.w + theta[3]);
        g[4] = __cosf(r1.x + theta[4]); g[5] = __cosf(r1.y + theta[5]);
        g[6] = __cosf(r1.z + theta[6]); g[7] = __cosf(r1.w + theta[7]);
        float h[NW];
        h[1] = g[0] * g[1]; h[2] = h[1] * g[2]; h[3] = h[2] * g[3];
        h[4] = h[3] * g[4]; h[5] = h[4] * g[5]; h[6] = h[5] * g[6];
        h[7] = h[6] * g[7];
        h[0] = (g[1] * g[2]) * (g[3] * g[4]) * ((g[5] * g[6]) * g[7]);
        const float mf = (mask[b * SS + row] != 0) ? 1.0f : 0.0f;
        // unmasked features to ws (q-side + K2)
        float* fo = ws + WS_FEAT + ((size_t)b * SS + row) * NW;
        *reinterpret_cast<float4*>(fo)     = make_float4(h[0], h[1], h[2], h[3]);
        *reinterpret_cast<float4*>(fo + 4) = make_float4(h[4], h[5], h[6], h[7]);
#pragma unroll
        for (int hd = 0; hd < NH; ++hd) {
            P[hd][tid][0] = h[2 * hd];
            P[hd][tid][1] = h[2 * hd + 1];
            P[hd][tid][2] = mf;
            P[hd][tid][3] = 0.0f;
        }
    }
    __syncthreads();

    // ---- partial moments: job = (head, m=(j,i)), kc = quarter of the 64 rows
    const int jm = tid >> 2;
    const int kc = tid & 3;
    float acc = 0.0f;
    if (jm < NJOB) {
        const int hh = jm / NM;
        int mm = jm % NM, s = 0;
        while (mm > s) { mm -= s + 1; ++s; }   // triangle decode
        const int j = mm, i = s - mm;          // j+i = s <= 9
        const bool j1 = j & 1, j2 = j & 2, j4 = j & 4, j8 = j & 8;
        const bool i1 = i & 1, i2 = i & 2, i4 = i & 4, i8 = i & 8;
#pragma unroll
        for (int it = 0; it < 16; ++it) {
            const int k = kc * 16 + it;
            const float4 uvm = *reinterpret_cast<const float4*>(&P[hh][k][0]);
            const float u = uvm.x, v = uvm.y, mf = uvm.z;
            const float u2 = u * u, u4 = u2 * u2, u8 = u4 * u4;
            const float v2 = v * v, v4 = v2 * v2, v8 = v4 * v4;
            float pu = (j1 ? u : 1.0f) * (j2 ? u2 : 1.0f);
            pu *= (j4 ? u4 : 1.0f); pu *= (j8 ? u8 : 1.0f);
            float pv = (i1 ? v : 1.0f) * (i2 ? v2 : 1.0f);
            pv *= (i4 ? v4 : 1.0f); pv *= (i8 ? v8 : 1.0f);
            acc = __builtin_fmaf(mf * pu, pv, acc);
        }
    }
    acc += __shfl_xor(acc, 1);
    acc += __shfl_xor(acc, 2);
    if (kc == 0 && jm < NJOB)
        ws[WS_PART + ((size_t)b * 16 + qc) * NJOB + jm] = acc;
}

// ---------------- K2: reduce moments, q-side dots, projection ----------------
__global__ __launch_bounds__(1024)
void mhaq_k2(const float* __restrict__ wout, const float* __restrict__ ws,
             float* __restrict__ out)
{
    __shared__ float Traw[NH][NM];
    __shared__ float Ts[NH][9][12], Ta[NH][9][12], Tb[NH][9][12];
    __shared__ float O[QB][NW];
    __shared__ float W[64];

    const int tid = threadIdx.x;
    const int b   = blockIdx.x >> 4;
    const int qc  = blockIdx.x & 15;

    // 1) sum the 16 partial tables for this b
    if (tid < NJOB) {
        const float* pp = ws + WS_PART + (size_t)b * 16 * NJOB + tid;
        float t = 0.0f;
#pragma unroll
        for (int s = 0; s < 16; ++s) t += pp[s * NJOB];
        Traw[tid / NM][tid % NM] = t;
    }
    if (tid < 64) W[tid] = wout[tid];
    __syncthreads();

    // 2) factorial-scaled tables over j+i<=8:
    //    Ts=T'[j][i]/(j!i!), Ta=T'[j+1][i]/(j!i!), Tb=T'[j][i+1]/(j!i!)
    if (tid < NH * 45) {
        const int hh = tid / 45;
        int mm = tid % 45, s = 0;
        while (mm > s) { mm -= s + 1; ++s; }
        const int j = mm, i = s - mm;          // j+i = s <= 8
        float fj = 1.0f, fi = 1.0f;
        for (int t = 2; t <= j; ++t) fj *= (float)t;
        for (int t = 2; t <= i; ++t) fi *= (float)t;
        const float invf = 1.0f / (fj * fi);
        const int id0 = s * (s + 1) / 2 + j;
        const int ida = (s + 1) * (s + 2) / 2 + (j + 1);
        const int idb = (s + 1) * (s + 2) / 2 + j;
        Ts[hh][j][i] = Traw[hh][id0] * invf;
        Ta[hh][j][i] = Traw[hh][ida] * invf;
        Tb[hh][j][i] = Traw[hh][idb] * invf;
    }
    __syncthreads();

    // 3) q-side: thread = (q, head, js); d = sum_{j,i} qfu^j qfv^i Ts[j][i], etc.
    const int q   = tid >> 4;
    const int hh2 = (tid >> 2) & 3;
    const int js  = tid & 3;
    const int row = qc * QB + q;
    const float* fq = ws + WS_FEAT + ((size_t)b * SS + row) * NW;
    const float CF = 0.70710678118654752f;  // 1/sqrt(2) folded into q
    const float qfu = fq[2 * hh2] * CF;
    const float qfv = fq[2 * hh2 + 1] * CF;

    float d = 0.0f, a0 = 0.0f, a1 = 0.0f;
    const float qfu2 = qfu * qfu;
    const float qfu4 = qfu2 * qfu2;
    float A = 1.0f;
    if (js & 1) A *= qfu;
    if (js & 2) A *= qfu2;
#pragma unroll
    for (int t = 0; t < 3; ++t) {
        const int j = js + 4 * t;
        if (j <= 8) {
            float f = A;
#pragma unroll
            for (int i = 0; i <= 8; ++i) {
                if (i <= 8 - j) {
                    d  = __builtin_fmaf(f, Ts[hh2][j][i], d);
                    a0 = __builtin_fmaf(f, Ta[hh2][j][i], a0);
                    a1 = __builtin_fmaf(f, Tb[hh2][j][i], a1);
                    f *= qfv;
                }
            }
        }
        A *= qfu4;
    }
    d  += __shfl_xor(d, 1);  d  += __shfl_xor(d, 2);
    a0 += __shfl_xor(a0, 1); a0 += __shfl_xor(a0, 2);
    a1 += __shfl_xor(a1, 1); a1 += __shfl_xor(a1, 2);
    if (js == 0) {
        const float inv = 1.0f / d;
        O[q][2 * hh2]     = a0 * inv;
        O[q][2 * hh2 + 1] = a1 * inv;
    }
    __syncthreads();

    // 4) projection: out = O @ W^T
    if (tid < QB * NW) {
        const int qq = tid >> 3, e = tid & 7;
        float sum = 0.0f;
#pragma unroll
        for (int f = 0; f < NW; ++f) sum = __builtin_fmaf(O[qq][f], W[e * NW + f], sum);
        out[((size_t)(b * SS + qc * QB + qq)) * NW + e] = sum;
    }
}

extern "C" void kernel_launch(void* const* d_in, const int* in_sizes, int n_in,
                              void* d_out, int out_size, void* d_ws, size_t ws_size,
                              hipStream_t stream) {
    const float* x     = (const float*)d_in[0];
    const int*   mask  = (const int*)d_in[1];
    const float* theta = (const float*)d_in[2];
    const float* wout  = (const float*)d_in[3];
    float* out = (float*)d_out;
    float* ws  = (float*)d_ws;

    dim3 grid(BB * (SS / QB));  // 256 blocks
    dim3 block(1024);
    mhaq_k1<<<grid, block, 0, stream>>>(x, mask, theta, ws);
    mhaq_k2<<<grid, block, 0, stream>>>(wout, ws, out);
}